// Round 10
// baseline (1304.317 us; speedup 1.0000x reference)
//
#include <hip/hip_runtime.h>

#define NB 262144
#define ZD 510
#define NK 128
#define GAP_THR 0.5f
#define CHW 68                    // padded row stride in ushorts (136 B)
#define CHUNK_USH (NK * CHW)      // 8704 ushorts per chunk image
#define CHUNK_U4  (CHUNK_USH / 8) // 1088 uint4

typedef _Float16 half8 __attribute__((ext_vector_type(8)));
typedef __attribute__((ext_vector_type(16))) float f32x16;

// ws layout: [0,512) csq | [512,+139264) cb16 image | [139776) cnt | [139840) list
#define WS_CB16_OFF 512
#define WS_CNT_OFF  139776
#define WS_LIST_OFF 139840

__device__ inline ushort f2h(float v) {
    return (ushort)__builtin_bit_cast(short, (_Float16)v);
}

// --- K0: csq (fp64, verified) + padded fp16 cb image (verified r7/r9) + cnt=0 ---
__global__ void prep_kernel(const float* __restrict__ cb, float* __restrict__ csq,
                            ushort* __restrict__ cb16, int* __restrict__ cnt) {
    const int code = blockIdx.x;
    const int tid  = threadIdx.x;
    if (code == 0 && tid == 0) cnt[0] = 0;
    const float* row = cb + (size_t)code * ZD;

    __shared__ double ws_red[4];
    double s = 0.0;
    for (int j = 0; j < 2; ++j) {
        int d = tid + (j << 8);
        if (d < ZD) { double v = (double)row[d]; s = fma(v, v, s); }
    }
#pragma unroll
    for (int m = 1; m <= 32; m <<= 1) s += __shfl_xor(s, m, 64);
    if ((tid & 63) == 0) ws_red[tid >> 6] = s;
    __syncthreads();
    if (tid == 0) csq[code] = (float)(ws_red[0] + ws_red[1] + ws_red[2] + ws_red[3]);

    for (int s2 = tid; s2 < 8 * CHW; s2 += 256) {
        int ch = s2 / CHW, off = s2 - ch * CHW;
        int d  = (ch << 6) + off;
        float v = (off < 64 && d < ZD) ? row[d] : 0.f;
        cb16[ch * CHUNK_USH + code * CHW + off] = f2h(v);
    }
}

// --- K1: fp16 MFMA + argmin + flag-to-list + gather; 512 thr = 8 waves, 256 rows ---
__global__ __launch_bounds__(512, 6) void vq_fused(
    const float* __restrict__ z, const float* __restrict__ cb,
    const uint4* __restrict__ cb16, const float* __restrict__ csq,
    int* __restrict__ cnt, int* __restrict__ list, float* __restrict__ out) {
    __shared__ __align__(16) ushort cbb[2][CHUNK_USH];   // 2 x 17408 B
    __shared__ int km[256];

    const int tid   = threadIdx.x;
    const int lane  = tid & 63;
    const int wv    = tid >> 6;               // 0..7
    const int cmod  = lane & 31;
    const int hi    = lane >> 5;
    const int brow0 = blockIdx.x << 8;        // 256 rows/block
    const int wrow0 = brow0 + (wv << 5);      // wave's 32 rows

    f32x16 acc[4];
#pragma unroll
    for (int cf = 0; cf < 4; ++cf)
#pragma unroll
        for (int e = 0; e < 16; ++e) acc[cf][e] = 0.f;

    const float* zrow = z + (size_t)(wrow0 + cmod) * ZD;

    float2 zr[2][16];
    // prologue: z chunk 0 + stage cbb[0]
#pragma unroll
    for (int t = 0; t < 4; ++t) {
        const int dbase = (t << 4) + (hi << 3);
        zr[0][t * 4 + 0] = *(const float2*)(zrow + dbase);
        zr[0][t * 4 + 1] = *(const float2*)(zrow + dbase + 2);
        zr[0][t * 4 + 2] = *(const float2*)(zrow + dbase + 4);
        zr[0][t * 4 + 3] = *(const float2*)(zrow + dbase + 6);
    }
    {
        uint4 cr0[3];
#pragma unroll
        for (int i = 0; i < 2; ++i) cr0[i] = cb16[(i << 9) + tid];
        if (tid < 64) cr0[2] = cb16[1024 + tid];
#pragma unroll
        for (int i = 0; i < 2; ++i) ((uint4*)cbb[0])[(i << 9) + tid] = cr0[i];
        if (tid < 64) ((uint4*)cbb[0])[1024 + tid] = cr0[2];
    }

#pragma unroll
    for (int c = 0; c < 8; ++c) {
        const int cur = c & 1, nxt = cur ^ 1;
        __syncthreads();                       // cbb[cur] visible; readers of cbb[nxt] done

        half8 afr[4];
#pragma unroll
        for (int t = 0; t < 4; ++t) {
            afr[t][0] = (_Float16)zr[cur][t * 4 + 0].x;
            afr[t][1] = (_Float16)zr[cur][t * 4 + 0].y;
            afr[t][2] = (_Float16)zr[cur][t * 4 + 1].x;
            afr[t][3] = (_Float16)zr[cur][t * 4 + 1].y;
            afr[t][4] = (_Float16)zr[cur][t * 4 + 2].x;
            afr[t][5] = (_Float16)zr[cur][t * 4 + 2].y;
            afr[t][6] = (_Float16)zr[cur][t * 4 + 3].x;
            afr[t][7] = (_Float16)zr[cur][t * 4 + 3].y;
        }

        // prefetch AFTER the barrier (r7 lesson): cb first, then z
        uint4 cr[3];
        if (c < 7) {
#pragma unroll
            for (int i = 0; i < 2; ++i) cr[i] = cb16[(c + 1) * CHUNK_U4 + (i << 9) + tid];
            if (tid < 64) cr[2] = cb16[(c + 1) * CHUNK_U4 + 1024 + tid];
            const int cg = (c + 1) << 6;
#pragma unroll
            for (int t = 0; t < 4; ++t) {
                const int dbase = cg + (t << 4) + (hi << 3);
                zr[nxt][t * 4 + 0] = *(const float2*)(zrow + dbase);
                zr[nxt][t * 4 + 1] = *(const float2*)(zrow + dbase + 2);
                zr[nxt][t * 4 + 2] = *(const float2*)(zrow + dbase + 4);
                zr[nxt][t * 4 + 3] = (dbase + 6 < ZD) ? *(const float2*)(zrow + dbase + 6)
                                                      : make_float2(0.f, 0.f);
            }
        }

        // 16 MFMA on cbb[cur] (conflict-free uint2-pair B reads, proven)
#pragma unroll
        for (int t = 0; t < 4; ++t) {
#pragma unroll
            for (int cf = 0; cf < 4; ++cf) {
                const int bbase = (cf * 32 + cmod) * CHW + (t << 4) + (hi << 3);
                union { uint2 u2[2]; half8 h; } b;
                b.u2[0] = *(const uint2*)&cbb[cur][bbase];
                b.u2[1] = *(const uint2*)&cbb[cur][bbase + 4];
                acc[cf] = __builtin_amdgcn_mfma_f32_32x32x16_f16(afr[t], b.h, acc[cf], 0, 0, 0);
            }
        }

        if (c < 7) {
#pragma unroll
            for (int i = 0; i < 2; ++i) ((uint4*)cbb[nxt])[(i << 9) + tid] = cr[i];
            if (tid < 64) ((uint4*)cbb[nxt])[1024 + tid] = cr[2];
        }
    }

    // ---- epilogue (verified logic; flag -> compact list) ----
    float cq[4];
#pragma unroll
    for (int cf = 0; cf < 4; ++cf) cq[cf] = csq[cf * 32 + cmod];

#pragma unroll
    for (int reg = 0; reg < 16; ++reg) {
        float bv = fmaf(-2.f, acc[0][reg], cq[0]);
        int   bk = cmod;
        float m2 = 1e30f;
#pragma unroll
        for (int cf = 1; cf < 4; ++cf) {
            float v = fmaf(-2.f, acc[cf][reg], cq[cf]);
            int  kk = cf * 32 + cmod;
            if (v < bv)      { m2 = bv; bv = v; bk = kk; }
            else if (v < m2) { m2 = v; }
        }
#pragma unroll
        for (int m = 1; m <= 16; m <<= 1) {
            float ov  = __shfl_xor(bv, m, 64);
            int   ok  = __shfl_xor(bk, m, 64);
            float om2 = __shfl_xor(m2, m, 64);
            float nm2 = fminf(fmaxf(bv, ov), fminf(m2, om2));
            bool take = (ov < bv) || (ov == bv && ok < bk);
            bv = take ? ov : bv;
            bk = take ? ok : bk;
            m2 = nm2;
        }
        if (cmod == 0) {
            int rloc = (reg & 3) + ((reg >> 2) << 3) + (hi << 2);
            km[(wv << 5) + rloc] = bk;
            if (m2 - bv < GAP_THR) {
                int idx = atomicAdd(cnt, 1);
                list[idx] = wrow0 + rloc;
            }
        }
    }
    __syncthreads();

    // gather write: 4 rows/pass, 128 threads/row, float2 (proven)
    const int half = tid >> 7, h = tid & 127;  // half 0..3
    for (int rp = 0; rp < 64; ++rp) {
        int row = (rp << 2) + half;
        int k   = km[row] & 127;
        const float2* src = (const float2*)(cb + (size_t)k * ZD);
        float2*       dst = (float2*)(out + (size_t)(brow0 + row) * ZD);
        dst[h] = src[h];
        if (h < 127) dst[128 + h] = src[128 + h];
    }
}

// --- K2: grid-strided wave-per-flagged-row exact fp32 repair (verified math) ---
__global__ __launch_bounds__(256) void repair(
    const float* __restrict__ z, const float* __restrict__ cb,
    const float* __restrict__ csq, const int* __restrict__ cnt,
    const int* __restrict__ list, float* __restrict__ out) {
    __shared__ float zsh[4][512];
    const int tid  = threadIdx.x;
    const int wv   = tid >> 6;
    const int lane = tid & 63;
    const int n    = cnt[0];
    const int gw0  = (blockIdx.x << 2) + wv;   // global wave id, 2048 waves

    for (int idx = gw0; idx < n; idx += 2048) {
        const int row = list[idx];
        const float* zr = z + (size_t)row * ZD;
#pragma unroll
        for (int j = 0; j < 8; ++j) {
            int d = (j << 6) + lane;
            zsh[wv][d] = (d < ZD) ? zr[d] : 0.f;
        }
        asm volatile("s_waitcnt lgkmcnt(0)" ::: "memory");

        float bv = 1e30f; int bk = 0;
        for (int c = 0; c < NK; ++c) {
            const float* cr = cb + (size_t)c * ZD;
            float s = 0.f;
#pragma unroll
            for (int j = 0; j < 8; ++j) {
                int d = (j << 6) + lane;
                float cv = (d < ZD) ? cr[d] : 0.f;
                s = fmaf(zsh[wv][d], cv, s);
            }
#pragma unroll
            for (int m = 1; m <= 32; m <<= 1) s += __shfl_xor(s, m, 64);
            float sc = fmaf(-2.f, s, csq[c]);
            if (sc < bv) { bv = sc; bk = c; }  // strict < keeps first index
        }
        const float2* src = (const float2*)(cb + (size_t)bk * ZD);
        float2*       dst = (float2*)(out + (size_t)row * ZD);
#pragma unroll
        for (int i = 0; i < 4; ++i) {
            int f2 = (i << 6) + lane;
            if (f2 < 255) dst[f2] = src[f2];
        }
    }
}

extern "C" void kernel_launch(void* const* d_in, const int* in_sizes, int n_in,
                              void* d_out, int out_size, void* d_ws, size_t ws_size,
                              hipStream_t stream) {
    const float* z  = (const float*)d_in[0];
    const float* cb = (const float*)d_in[1];
    float*  out  = (float*)d_out;
    float*  csq  = (float*)d_ws;
    ushort* cb16 = (ushort*)((char*)d_ws + WS_CB16_OFF);
    int*    cnt  = (int*)((char*)d_ws + WS_CNT_OFF);
    int*    list = (int*)((char*)d_ws + WS_LIST_OFF);

    prep_kernel<<<NK, 256, 0, stream>>>(cb, csq, cb16, cnt);
    vq_fused<<<NB / 256, 512, 0, stream>>>(z, cb, (const uint4*)cb16, csq, cnt, list, out);
    repair<<<512, 256, 0, stream>>>(z, cb, csq, cnt, list, out);
}

// Round 11
// 477.488 us; speedup vs baseline: 2.7316x; 2.7316x over previous
//
#include <hip/hip_runtime.h>

#define NB 262144
#define ZD 510
#define NK 128
#define GAP_THR 0.5f
#define CHW 68                    // padded row stride in ushorts (136 B)
#define CHUNK_USH (NK * CHW)      // 8704 ushorts per chunk image
#define CHUNK_U4  (CHUNK_USH / 8) // 1088 uint4

typedef _Float16 half8 __attribute__((ext_vector_type(8)));
typedef __attribute__((ext_vector_type(16))) float f32x16;

// ws layout: [0,512) csq | [512,+139264) cb16 image | [139776) cnt | [139840) list
#define WS_CB16_OFF 512
#define WS_CNT_OFF  139776
#define WS_LIST_OFF 139840

__device__ inline ushort f2h(float v) {
    return (ushort)__builtin_bit_cast(short, (_Float16)v);
}

// --- K0: csq (fp64, verified) + padded fp16 cb image (verified) + cnt=0 ---
__global__ void prep_kernel(const float* __restrict__ cb, float* __restrict__ csq,
                            ushort* __restrict__ cb16, int* __restrict__ cnt) {
    const int code = blockIdx.x;
    const int tid  = threadIdx.x;
    if (code == 0 && tid == 0) cnt[0] = 0;
    const float* row = cb + (size_t)code * ZD;

    __shared__ double ws_red[4];
    double s = 0.0;
    for (int j = 0; j < 2; ++j) {
        int d = tid + (j << 8);
        if (d < ZD) { double v = (double)row[d]; s = fma(v, v, s); }
    }
#pragma unroll
    for (int m = 1; m <= 32; m <<= 1) s += __shfl_xor(s, m, 64);
    if ((tid & 63) == 0) ws_red[tid >> 6] = s;
    __syncthreads();
    if (tid == 0) csq[code] = (float)(ws_red[0] + ws_red[1] + ws_red[2] + ws_red[3]);

    for (int s2 = tid; s2 < 8 * CHW; s2 += 256) {
        int ch = s2 / CHW, off = s2 - ch * CHW;
        int d  = (ch << 6) + off;
        float v = (off < 64 && d < ZD) ? row[d] : 0.f;
        cb16[ch * CHUNK_USH + code * CHW + off] = f2h(v);
    }
}

// --- K1: fp16 MFMA + argmin + flag-to-list + gather; 512 thr, no-spill TLP ---
__global__ __launch_bounds__(512, 4) void vq_fused(
    const float* __restrict__ z, const float* __restrict__ cb,
    const uint4* __restrict__ cb16, const float* __restrict__ csq,
    int* __restrict__ cnt, int* __restrict__ list, float* __restrict__ out) {
    __shared__ __align__(16) ushort cbb[2][CHUNK_USH];   // 2 x 17408 B
    __shared__ int km[256];

    const int tid   = threadIdx.x;
    const int lane  = tid & 63;
    const int wv    = tid >> 6;               // 0..7
    const int cmod  = lane & 31;
    const int hi    = lane >> 5;
    const int brow0 = blockIdx.x << 8;        // 256 rows/block
    const int wrow0 = brow0 + (wv << 5);      // wave's 32 rows

    f32x16 acc[4];
#pragma unroll
    for (int cf = 0; cf < 4; ++cf)
#pragma unroll
        for (int e = 0; e < 16; ++e) acc[cf][e] = 0.f;

    const float* zrow = z + (size_t)(wrow0 + cmod) * ZD;

    // prologue: stage cbb[0] only
    {
        uint4 cr0[3];
#pragma unroll
        for (int i = 0; i < 2; ++i) cr0[i] = cb16[(i << 9) + tid];
        if (tid < 64) cr0[2] = cb16[1024 + tid];
#pragma unroll
        for (int i = 0; i < 2; ++i) ((uint4*)cbb[0])[(i << 9) + tid] = cr0[i];
        if (tid < 64) ((uint4*)cbb[0])[1024 + tid] = cr0[2];
    }

#pragma unroll
    for (int c = 0; c < 8; ++c) {
        const int cur = c & 1, nxt = cur ^ 1;
        __syncthreads();                       // cbb[cur] visible; readers of cbb[nxt] done

        // z loads for THIS chunk issue first (critical path; FIFO vmcnt lets
        // the conversion wait on these while cr stays in flight)
        const int cg = c << 6;
        float2 zr[16];
#pragma unroll
        for (int t = 0; t < 4; ++t) {
            const int dbase = cg + (t << 4) + (hi << 3);
            zr[t * 4 + 0] = *(const float2*)(zrow + dbase);
            zr[t * 4 + 1] = *(const float2*)(zrow + dbase + 2);
            zr[t * 4 + 2] = *(const float2*)(zrow + dbase + 4);
            zr[t * 4 + 3] = (dbase + 6 < ZD) ? *(const float2*)(zrow + dbase + 6)
                                             : make_float2(0.f, 0.f);
        }
        // cb prefetch for next chunk (consumed after the MFMA block)
        uint4 cr[3];
        if (c < 7) {
#pragma unroll
            for (int i = 0; i < 2; ++i) cr[i] = cb16[(c + 1) * CHUNK_U4 + (i << 9) + tid];
            if (tid < 64) cr[2] = cb16[(c + 1) * CHUNK_U4 + 1024 + tid];
        }

        half8 afr[4];
#pragma unroll
        for (int t = 0; t < 4; ++t) {
            afr[t][0] = (_Float16)zr[t * 4 + 0].x;
            afr[t][1] = (_Float16)zr[t * 4 + 0].y;
            afr[t][2] = (_Float16)zr[t * 4 + 1].x;
            afr[t][3] = (_Float16)zr[t * 4 + 1].y;
            afr[t][4] = (_Float16)zr[t * 4 + 2].x;
            afr[t][5] = (_Float16)zr[t * 4 + 2].y;
            afr[t][6] = (_Float16)zr[t * 4 + 3].x;
            afr[t][7] = (_Float16)zr[t * 4 + 3].y;
        }

        // 16 MFMA on cbb[cur] (conflict-free uint2-pair B reads, proven)
#pragma unroll
        for (int t = 0; t < 4; ++t) {
#pragma unroll
            for (int cf = 0; cf < 4; ++cf) {
                const int bbase = (cf * 32 + cmod) * CHW + (t << 4) + (hi << 3);
                union { uint2 u2[2]; half8 h; } b;
                b.u2[0] = *(const uint2*)&cbb[cur][bbase];
                b.u2[1] = *(const uint2*)&cbb[cur][bbase + 4];
                acc[cf] = __builtin_amdgcn_mfma_f32_32x32x16_f16(afr[t], b.h, acc[cf], 0, 0, 0);
            }
        }

        if (c < 7) {
#pragma unroll
            for (int i = 0; i < 2; ++i) ((uint4*)cbb[nxt])[(i << 9) + tid] = cr[i];
            if (tid < 64) ((uint4*)cbb[nxt])[1024 + tid] = cr[2];
        }
    }

    // ---- epilogue (verified logic; flag -> compact list) ----
    float cq[4];
#pragma unroll
    for (int cf = 0; cf < 4; ++cf) cq[cf] = csq[cf * 32 + cmod];

#pragma unroll
    for (int reg = 0; reg < 16; ++reg) {
        float bv = fmaf(-2.f, acc[0][reg], cq[0]);
        int   bk = cmod;
        float m2 = 1e30f;
#pragma unroll
        for (int cf = 1; cf < 4; ++cf) {
            float v = fmaf(-2.f, acc[cf][reg], cq[cf]);
            int  kk = cf * 32 + cmod;
            if (v < bv)      { m2 = bv; bv = v; bk = kk; }
            else if (v < m2) { m2 = v; }
        }
#pragma unroll
        for (int m = 1; m <= 16; m <<= 1) {
            float ov  = __shfl_xor(bv, m, 64);
            int   ok  = __shfl_xor(bk, m, 64);
            float om2 = __shfl_xor(m2, m, 64);
            float nm2 = fminf(fmaxf(bv, ov), fminf(m2, om2));
            bool take = (ov < bv) || (ov == bv && ok < bk);
            bv = take ? ov : bv;
            bk = take ? ok : bk;
            m2 = nm2;
        }
        if (cmod == 0) {
            int rloc = (reg & 3) + ((reg >> 2) << 3) + (hi << 2);
            km[(wv << 5) + rloc] = bk;
            if (m2 - bv < GAP_THR) {
                int idx = atomicAdd(cnt, 1);
                list[idx] = wrow0 + rloc;
            }
        }
    }
    __syncthreads();

    // gather write: 4 rows/pass, 128 threads/row, float2 (proven)
    const int half = tid >> 7, h = tid & 127;  // half 0..3
    for (int rp = 0; rp < 64; ++rp) {
        int row = (rp << 2) + half;
        int k   = km[row] & 127;
        const float2* src = (const float2*)(cb + (size_t)k * ZD);
        float2*       dst = (float2*)(out + (size_t)(brow0 + row) * ZD);
        dst[h] = src[h];
        if (h < 127) dst[128 + h] = src[128 + h];
    }
}

// --- K2: grid-strided wave-per-flagged-row exact fp32 repair (verified math) ---
__global__ __launch_bounds__(256) void repair(
    const float* __restrict__ z, const float* __restrict__ cb,
    const float* __restrict__ csq, const int* __restrict__ cnt,
    const int* __restrict__ list, float* __restrict__ out) {
    __shared__ float zsh[4][512];
    const int tid  = threadIdx.x;
    const int wv   = tid >> 6;
    const int lane = tid & 63;
    const int n    = cnt[0];
    const int gw0  = (blockIdx.x << 2) + wv;   // global wave id, 2048 waves

    for (int idx = gw0; idx < n; idx += 2048) {
        const int row = list[idx];
        const float* zr = z + (size_t)row * ZD;
#pragma unroll
        for (int j = 0; j < 8; ++j) {
            int d = (j << 6) + lane;
            zsh[wv][d] = (d < ZD) ? zr[d] : 0.f;
        }
        asm volatile("s_waitcnt lgkmcnt(0)" ::: "memory");

        float bv = 1e30f; int bk = 0;
        for (int c = 0; c < NK; ++c) {
            const float* cr = cb + (size_t)c * ZD;
            float s = 0.f;
#pragma unroll
            for (int j = 0; j < 8; ++j) {
                int d = (j << 6) + lane;
                float cv = (d < ZD) ? cr[d] : 0.f;
                s = fmaf(zsh[wv][d], cv, s);
            }
#pragma unroll
            for (int m = 1; m <= 32; m <<= 1) s += __shfl_xor(s, m, 64);
            float sc = fmaf(-2.f, s, csq[c]);
            if (sc < bv) { bv = sc; bk = c; }  // strict < keeps first index
        }
        const float2* src = (const float2*)(cb + (size_t)bk * ZD);
        float2*       dst = (float2*)(out + (size_t)row * ZD);
#pragma unroll
        for (int i = 0; i < 4; ++i) {
            int f2 = (i << 6) + lane;
            if (f2 < 255) dst[f2] = src[f2];
        }
    }
}

extern "C" void kernel_launch(void* const* d_in, const int* in_sizes, int n_in,
                              void* d_out, int out_size, void* d_ws, size_t ws_size,
                              hipStream_t stream) {
    const float* z  = (const float*)d_in[0];
    const float* cb = (const float*)d_in[1];
    float*  out  = (float*)d_out;
    float*  csq  = (float*)d_ws;
    ushort* cb16 = (ushort*)((char*)d_ws + WS_CB16_OFF);
    int*    cnt  = (int*)((char*)d_ws + WS_CNT_OFF);
    int*    list = (int*)((char*)d_ws + WS_LIST_OFF);

    prep_kernel<<<NK, 256, 0, stream>>>(cb, csq, cb16, cnt);
    vq_fused<<<NB / 256, 512, 0, stream>>>(z, cb, (const uint4*)cb16, csq, cnt, list, out);
    repair<<<512, 256, 0, stream>>>(z, cb, csq, cnt, list, out);
}